// Round 11
// baseline (150.201 us; speedup 1.0000x reference)
//
#include <hip/hip_runtime.h>
#include <stdint.h>

#define EPS_F 1e-7f

typedef float f32x16 __attribute__((ext_vector_type(16)));
typedef int   v8i    __attribute__((ext_vector_type(8)));

// 8 consecutive VGPRs: two b128 loads land directly in the MFMA operand tuple.
union A32 { uint4 u4[2]; v8i v; };

__device__ __forceinline__ unsigned cvt4(float a, float b, float c, float d) {
  int v = __builtin_amdgcn_cvt_pk_fp8_f32(a, b, 0, false);   // bytes 0,1
  return (unsigned)__builtin_amdgcn_cvt_pk_fp8_f32(c, d, v, true);  // bytes 2,3
}

// MX-scaled fp8 MFMA, 32x32 K=64, scales = 1.0 (e8m0 127 everywhere).
// 131072 FLOP/inst = 2x the 16x16x128 at the same measured rate (m59: 4686 TF).
#define MFMA3264(A, B, C) __builtin_amdgcn_mfma_scale_f32_32x32x64_f8f6f4( \
    (A), (B), (C), 0, 0, 0, 0x7F7F7F7F, 0, 0x7F7F7F7F)

// ---------------------------------------------------------------------------
// Software k-order, shared by BOTH operands (same cancellation argument as
// the R5-R10 validated 16x16x128 version): lane l supplies A-row (l&31) and
// B-col (l&31); hi = l>>5 selects the k-half; nominal k = kb*64 + hi*32 + b,
// b in [0,32).  16-B granule index k16 = kb*4 + hi*2 + p  (p = which b128).
// A LDS image:  As[k16*128 + rf*32 + ((r31 + k16) & 31)]   (rotation swizzle
//   spreads banks on both the staging writes and the main-loop reads).
// B image:      Bg[(g*8 + kb)*128 + hi*64 + p*32 + c31]    (1 MB linear).
// ---------------------------------------------------------------------------

// ---------------------------------------------------------------------------
// prep: protos fp32 (2048x512) -> fp8 e4m3 B image in the layout above.
// Lane l of proto c holds k [8l, 8l+8) -> k16 = l>>1, half (l&1):
//   kb = l>>3, hi = (l>>2)&1, p = (l>>1)&1 -> one aligned uint2 store.
// Also y2[c], ry[c] = 1/(1-y2), out = 0.
// ---------------------------------------------------------------------------
__global__ __launch_bounds__(256) void prep_kernel(
    const float* __restrict__ protos, uint8_t* __restrict__ wsB,
    float* __restrict__ y2a, float* __restrict__ rya,
    float* __restrict__ out) {
  const int lane = threadIdx.x & 63;
  const int w    = threadIdx.x >> 6;
  const int c    = blockIdx.x * 4 + w;
  const int g    = c >> 5, c31 = c & 31;
  const float4* p = (const float4*)(protos + (size_t)c * 512 + lane * 8);
  float4 f0 = p[0], f1 = p[1];
  float s = f0.x*f0.x + f0.y*f0.y + f0.z*f0.z + f0.w*f0.w
          + f1.x*f1.x + f1.y*f1.y + f1.z*f1.z + f1.w*f1.w;
#pragma unroll
  for (int off = 32; off > 0; off >>= 1) s += __shfl_xor(s, off, 64);
  if (lane == 0) { y2a[c] = s; rya[c] = 1.f / (1.f - s); }
  unsigned ux = cvt4(f0.x, f0.y, f0.z, f0.w);   // k [8l, 8l+4)
  unsigned uy = cvt4(f1.x, f1.y, f1.z, f1.w);   // k [8l+4, 8l+8)
  const int kb = lane >> 3, hi = (lane >> 2) & 1, pp = (lane >> 1) & 1;
  size_t ri  = ((size_t)(g * 8 + kb)) * 128 + hi * 64 + pp * 32 + c31;
  *(uint2*)(wsB + ri * 16 + (lane & 1) * 8) = make_uint2(ux, uy);
  if (blockIdx.x == 0 && threadIdx.x == 0) out[0] = 0.f;
}

// ---------------------------------------------------------------------------
// gemm_min v11: 32x32x64 MFMA — HALVE THE INSTRUCTION COUNT.
// 256 blocks x 256 thr (4 waves), launch_bounds(256,1).
// ROUND-10 DIAGNOSIS (session-wide): seven variants pin at ~60 us; occupancy
// 1 vs 4 waves/SIMD identical; LDS and B traffic each halved with no effect.
// The invariant: 1024 MFMA inst/SIMD at wall = 140 cyc/inst vs 34.5 pipe —
// a fixed ~105-cyc per-INSTRUCTION overhead (issue + operand staging +
// exposed waits) is the binding cost.  R0 (16x16x32) fits the same model:
// 4096 inst at ~44 cyc/inst.  Fix: 32x32x64 scaled MFMA = 2x FLOP/inst at
// the same pipe rate -> 512 inst/SIMD.  Predict wall 512 x (69 + ~100) =
// ~38-45 us.  If unchanged -> per-CU shared limit -> this structure is at
// its practical roofline.
//   - tile 128 rows x 2048 cols (256 MB B demand, R10-proven irrelevant);
//     wave w = col strip [w*512,+512) = 16 colfrags of 32; rf = 4 row-frags.
//   - per kb-step (K=64): 8 ds_read_b128 (A, 4 rf x 2) + 2 global b128
//     (B depth-2 pipeline, slot kb&1) + 4 MFMA.
//   - A staged via the R9/R10-verified coalesced 4-lane transpose into the
//     rotation-swizzled image; x2 fp32-exact inline; ONE barrier.
//   - regs: acc 4x16=64 + tmin 4x16=64 + Bp 16 + temps -> ~240 at cap 256;
//     WRITE_SIZE in MB => spill => abort.
//   - epilogue per colfrag: x2 via broadcast float4 LDS reads (rows
//     rf*32 + rg*8 + hi*4 + j); tmin folded in-register; final min across
//     the 32 col-lanes by shfl_xor(1..16).
// ---------------------------------------------------------------------------
__global__ __launch_bounds__(256, 1) void gemm_min_kernel(
    const float* __restrict__ z, const uint8_t* __restrict__ wsB,
    const float* __restrict__ y2a, const float* __restrict__ rya,
    const float* __restrict__ marg, float* __restrict__ out) {
  __shared__ uint4 As[4096];     // k16*128 + rf*32 + ((r31+k16)&31)   64 KB
  __shared__ float x2s[128];
  __shared__ float rxs[128];
  __shared__ float minbuf[128][4];

  const int tid  = threadIdx.x;
  const int lane = tid & 63;
  const int w    = tid >> 6;          // wave 0..3
  const int c31  = lane & 31;         // A-row / B-col within fragment
  const int hi   = lane >> 5;         // k-half
  const size_t rowbase = (size_t)blockIdx.x * 128;

  const uint4* Bg = (const uint4*)wsB;

  // ---- B warm-up (steps 0,1): g = w*16, kb = 0,1 ----
  A32 Bp[2];
#pragma unroll
  for (int i = 0; i < 2; ++i) {
    size_t r0 = ((size_t)(w * 16) * 8 + i) * 128 + hi * 64 + c31;
    Bp[i].u4[0] = Bg[r0];
    Bp[i].u4[1] = Bg[r0 + 32];
  }

  // ---- A staging (R9/R10-verified transpose), new swizzled image ----
  // wave w owns rows [w*32,+32), two per super-step; granule after the
  // 4-lane transpose: row r31 = 2ss+(c4>>1), k16 = (c4&1)*16 + m.
  {
    const int c4 = lane & 3;
    const int m  = lane >> 2;           // 0..15
    const float* zb = z + (rowbase + w * 32) * 512 + lane * 4;
#pragma unroll
    for (int ss = 0; ss < 16; ++ss) {
      float4 f0 = *(const float4*)(zb + (2 * ss + 0) * 512);
      float4 f1 = *(const float4*)(zb + (2 * ss + 0) * 512 + 256);
      float4 f2 = *(const float4*)(zb + (2 * ss + 1) * 512);
      float4 f3 = *(const float4*)(zb + (2 * ss + 1) * 512 + 256);
      float sa = f0.x*f0.x + f0.y*f0.y + f0.z*f0.z + f0.w*f0.w
               + f1.x*f1.x + f1.y*f1.y + f1.z*f1.z + f1.w*f1.w;
      float sb = f2.x*f2.x + f2.y*f2.y + f2.z*f2.z + f2.w*f2.w
               + f3.x*f3.x + f3.y*f3.y + f3.z*f3.z + f3.w*f3.w;
#pragma unroll
      for (int off = 32; off > 0; off >>= 1) {
        sa += __shfl_xor(sa, off, 64);
        sb += __shfl_xor(sb, off, 64);
      }
      if (lane == 0) {
        int r0 = w * 32 + 2 * ss;
        x2s[r0] = sa;     rxs[r0] = 1.f / (1.f - sa);
        x2s[r0 + 1] = sb; rxs[r0 + 1] = 1.f / (1.f - sb);
      }
      unsigned v0 = cvt4(f0.x, f0.y, f0.z, f0.w);
      unsigned v1 = cvt4(f1.x, f1.y, f1.z, f1.w);
      unsigned v2 = cvt4(f2.x, f2.y, f2.z, f2.w);
      unsigned v3 = cvt4(f3.x, f3.y, f3.z, f3.w);
      unsigned t;
      t = (unsigned)__shfl_xor((int)((c4 & 1) ? v0 : v1), 1, 64);
      if (c4 & 1) v0 = t; else v1 = t;
      t = (unsigned)__shfl_xor((int)((c4 & 1) ? v2 : v3), 1, 64);
      if (c4 & 1) v2 = t; else v3 = t;
      t = (unsigned)__shfl_xor((int)((c4 & 2) ? v0 : v2), 2, 64);
      if (c4 & 2) v0 = t; else v2 = t;
      t = (unsigned)__shfl_xor((int)((c4 & 2) ? v1 : v3), 2, 64);
      if (c4 & 2) v1 = t; else v3 = t;
      int k16 = ((c4 & 1) << 4) + m;
      int r31 = 2 * ss + (c4 >> 1);
      int ri  = k16 * 128 + w * 32 + ((r31 + k16) & 31);
      As[ri] = make_uint4(v0, v1, v2, v3);
    }
  }
  __syncthreads();  // the ONLY barrier before the final reduction

  float tmin[4][16];
#pragma unroll
  for (int rf = 0; rf < 4; ++rf)
#pragma unroll
    for (int r = 0; r < 16; ++r) tmin[rf][r] = 3.4e38f;

  const float* y2p = y2a + w * 512 + c31;
  const float* ryp = rya + w * 512 + c31;

#pragma clang loop unroll(disable)
  for (int s = 0; s < 16; ++s) {
    f32x16 acc[4];
#pragma unroll
    for (int rf = 0; rf < 4; ++rf) {
      f32x16 zz = {0.f};
      acc[rf] = zz;
    }
    float y2v = y2p[s * 32], ryv = ryp[s * 32];

#pragma unroll
    for (int kb = 0; kb < 8; ++kb) {
      v8i bv = Bp[kb & 1].v;
      {  // prefetch step i+2 into the just-consumed slot (pad absorbs tail)
        int ip = s * 8 + kb + 2;
        size_t r0 = ((size_t)(w * 16 + (ip >> 3)) * 8 + (ip & 7)) * 128
                  + hi * 64 + c31;
        Bp[kb & 1].u4[0] = Bg[r0];
        Bp[kb & 1].u4[1] = Bg[r0 + 32];
      }
      const int k0 = kb * 4 + hi * 2;
#pragma unroll
      for (int rf = 0; rf < 4; ++rf) {
        A32 a;
        a.u4[0] = As[(k0    ) * 128 + rf * 32 + ((c31 + k0    ) & 31)];
        a.u4[1] = As[(k0 + 1) * 128 + rf * 32 + ((c31 + k0 + 1) & 31)];
        acc[rf] = MFMA3264(a.v, bv, acc[rf]);
      }
    }

    // epilogue: cols c = w*512 + s*32 + c31; rows rf*32 + rg*8 + hi*4 + j
#pragma unroll
    for (int rf = 0; rf < 4; ++rf) {
#pragma unroll
      for (int rg = 0; rg < 4; ++rg) {
        float4 x4 = *(const float4*)&x2s[rf * 32 + rg * 8 + hi * 4];
        float u0 = fmaxf(fmaf(-2.f, acc[rf][rg * 4 + 0], x4.x + y2v), 0.f) * ryv;
        float u1 = fmaxf(fmaf(-2.f, acc[rf][rg * 4 + 1], x4.y + y2v), 0.f) * ryv;
        float u2 = fmaxf(fmaf(-2.f, acc[rf][rg * 4 + 2], x4.z + y2v), 0.f) * ryv;
        float u3 = fmaxf(fmaf(-2.f, acc[rf][rg * 4 + 3], x4.w + y2v), 0.f) * ryv;
        tmin[rf][rg * 4 + 0] = fminf(tmin[rf][rg * 4 + 0], u0);
        tmin[rf][rg * 4 + 1] = fminf(tmin[rf][rg * 4 + 1], u1);
        tmin[rf][rg * 4 + 2] = fminf(tmin[rf][rg * 4 + 2], u2);
        tmin[rf][rg * 4 + 3] = fminf(tmin[rf][rg * 4 + 3], u3);
      }
    }
  }

  // ---- min across the 32 col-lanes sharing each row ----
#pragma unroll
  for (int rf = 0; rf < 4; ++rf) {
#pragma unroll
    for (int r = 0; r < 16; ++r) {
      float v = tmin[rf][r];
      v = fminf(v, __shfl_xor(v, 1, 64));
      v = fminf(v, __shfl_xor(v, 2, 64));
      v = fminf(v, __shfl_xor(v, 4, 64));
      v = fminf(v, __shfl_xor(v, 8, 64));
      v = fminf(v, __shfl_xor(v, 16, 64));
      if (c31 == 0)
        minbuf[rf * 32 + (r & 3) + 8 * (r >> 2) + 4 * hi][w] = v;
    }
  }
  __syncthreads();

  if (w < 2) {  // rows 0..127: wave w covers rows w*64 + lane
    int row = w * 64 + lane;
    float m = fminf(fminf(minbuf[row][0], minbuf[row][1]),
                    fminf(minbuf[row][2], minbuf[row][3]));
    float t = m * rxs[row];                  // fold 1/(1-x2) once per row
    float arg = fmaxf(fmaf(2.f, t, 1.f), 1.f + EPS_F);
    float contrib = fmaxf(marg[0] - acoshf(arg), 0.f);
#pragma unroll
    for (int off = 32; off > 0; off >>= 1) contrib += __shfl_xor(contrib, off, 64);
    if (lane == 0) atomicAdd(out, contrib * (1.0f / 32768.f));
  }
}

// ---------------------------------------------------------------------------
extern "C" void kernel_launch(void* const* d_in, const int* in_sizes, int n_in,
                              void* d_out, int out_size, void* d_ws, size_t ws_size,
                              hipStream_t stream) {
  const float* z      = (const float*)d_in[0];  // 32768 x 512 fp32
  const float* protos = (const float*)d_in[1];  // 2048 x 512 fp32
  const float* marg   = (const float*)d_in[2];  // scalar
  float* out = (float*)d_out;
  uint8_t* wsB = (uint8_t*)d_ws;                // 1 MB image
  // 192 KB pad absorbs the harmless B-pipeline tail over-reads (<= 40 KB).
  float* y2a = (float*)((char*)d_ws + (1 << 20) + 192 * 1024);   // 8 KB
  float* rya = y2a + 2048;                                       // 8 KB

  prep_kernel<<<512, 256, 0, stream>>>(protos, wsB, y2a, rya, out);
  gemm_min_kernel<<<256, 256, 0, stream>>>(z, wsB, y2a, rya, marg, out);
}

// Round 12
// 129.097 us; speedup vs baseline: 1.1635x; 1.1635x over previous
//
#include <hip/hip_runtime.h>
#include <stdint.h>

#define EPS_F 1e-7f

typedef float f32x4 __attribute__((ext_vector_type(4)));
typedef int   v8i   __attribute__((ext_vector_type(8)));

// 8 consecutive VGPRs: two b128 loads land directly in the MFMA operand tuple.
union A32 { uint4 u4[2]; v8i v; };

__device__ __forceinline__ unsigned cvt4(float a, float b, float c, float d) {
  int v = __builtin_amdgcn_cvt_pk_fp8_f32(a, b, 0, false);   // bytes 0,1
  return (unsigned)__builtin_amdgcn_cvt_pk_fp8_f32(c, d, v, true);  // bytes 2,3
}

// MX-scaled fp8 MFMA, K=128, scales = 1.0 (e8m0 127 in every byte -> opsel-proof).
#define MFMA128(A, B, C) __builtin_amdgcn_mfma_scale_f32_16x16x128_f8f6f4( \
    (A), (B), (C), 0, 0, 0, 0x7F7F7F7F, 0, 0x7F7F7F7F)

// ---------------------------------------------------------------------------
// Shared software k-order for BOTH operand images (R5-R10 verified, absmax 0):
//   fragment lane = kg*16 + (row|col)&15,  kg = lane>>4
//   nominal k  = kb*128 + kg*32 + j,  j in [0,32)
//   j in [0,16)  -> LO plane,  j in [16,32) -> HI plane
// B image: run index ri = (g*4 + kb)*64 + lane, planes of 512 KB each.
// ---------------------------------------------------------------------------

// ---------------------------------------------------------------------------
// prep: protos fp32 (2048x512) -> fp8 e4m3 B image (unchanged from R5).
// ---------------------------------------------------------------------------
__global__ __launch_bounds__(256) void prep_kernel(
    const float* __restrict__ protos, uint8_t* __restrict__ wsB,
    float* __restrict__ y2a, float* __restrict__ rya,
    float* __restrict__ out) {
  const int lane = threadIdx.x & 63;
  const int w    = threadIdx.x >> 6;
  const int c    = blockIdx.x * 4 + w;
  const int g    = c >> 4, cl = c & 15;
  const float4* p = (const float4*)(protos + (size_t)c * 512 + lane * 8);
  float4 f0 = p[0], f1 = p[1];
  float s = f0.x*f0.x + f0.y*f0.y + f0.z*f0.z + f0.w*f0.w
          + f1.x*f1.x + f1.y*f1.y + f1.z*f1.z + f1.w*f1.w;
#pragma unroll
  for (int off = 32; off > 0; off >>= 1) s += __shfl_xor(s, off, 64);
  if (lane == 0) { y2a[c] = s; rya[c] = 1.f / (1.f - s); }
  unsigned ux = cvt4(f0.x, f0.y, f0.z, f0.w);   // k [8l, 8l+4)
  unsigned uy = cvt4(f1.x, f1.y, f1.z, f1.w);   // k [8l+4, 8l+8)
  const int kb = lane >> 4, kg = (lane >> 2) & 3, bo = lane & 3;
  size_t ri  = (size_t)(g * 4 + kb) * 64 + kg * 16 + cl;
  size_t off = ri * 16 + (size_t)(bo & 1) * 8 + (size_t)(bo >> 1) * (512u * 1024u);
  *(uint2*)(wsB + off) = make_uint2(ux, uy);
  if (blockIdx.x == 0 && threadIdx.x == 0) out[0] = 0.f;
}

// ---------------------------------------------------------------------------
// gemm_min v12: PHASE-ROTATED WAVES + SETPRIO.  Base = R9 (best, 60 us,
// VGPR 128 no spill).  512 blocks x 512 thr (8 waves), launch_bounds(512,1).
// ROUND-11 DIAGNOSIS (session-wide): MFMA busy time is pinned at ~13 us (=
// the MX pipe floor) across 0.5M/1M/4M-instruction variants, 1-4 waves/SIMD,
// 2x LDS traffic, 2x B traffic -> no per-resource average is binding.  The
// invariant left: all waves run the SAME instruction stream from the same
// barrier -> synchronized {ds burst | vmcnt wait | MFMA burst} phases; the
// pipe idles between collective bursts (m233-style phase stall).  Fix at
// zero algorithmic cost, exploiting min-reduction order-invariance:
//   - wave w iterates s in ROTATED order s = (t+w)&7 -> the 8 waves sit
//     permanently in 8 different phases (B/LDS/MFMA activity interleaved
//     across the CU at every instant).
//   - T5 s_setprio(1) around each MFMA cluster: with role diversity now
//     present, MFMA-ready waves win issue arbitration (guide: +21-39% on
//     phase-split schedules, null on lockstep -> this is also a clean test
//     of the mechanism).
// Everything else byte-identical to R9 (coalesced transpose staging, depth-2
// B pipeline, one barrier).  Rotation wrap (t'=8 -> s'=w) stays in-bounds.
// ---------------------------------------------------------------------------
__global__ __launch_bounds__(512, 1) void gemm_min_kernel(
    const float* __restrict__ z, const uint8_t* __restrict__ wsB,
    const float* __restrict__ y2a, const float* __restrict__ rya,
    const float* __restrict__ marg, float* __restrict__ out) {
  __shared__ uint4 As2[2048];    // [pl*1024 + (kb*4+rf)*64 + kg*16 + r15]  32 KB
  __shared__ float x2s[64];
  __shared__ float rxs[64];
  __shared__ float minbuf[64][8];

  const int tid  = threadIdx.x;
  const int lane = tid & 63;
  const int w    = tid >> 6;          // wave 0..7
  const int q    = lane >> 4;         // kg / acc row-group
  const int l15  = lane & 15;
  const size_t rowbase = (size_t)blockIdx.x * 64;

  const uint4* BLo = (const uint4*)wsB;
  const uint4* BHi = BLo + 32768;     // +512 KB

  // ---- B warm-up (rotated steps t=0, kb=0,1): s0 = w ----
  // wave w owns cols [w*256,+256): frag pair g0 = w*16 + 2s, g1 = g0+1.
  // chunk(s,kb) = w*64 + s*8 + kb; slot = (t*4+kb)&1 = kb&1.
  A32 Bp0[2], Bp1[2];
#pragma unroll
  for (int i = 0; i < 2; ++i) {
    size_t r0 = (size_t)(w * 64 + (w & 7) * 8 + i) * 64 + lane;
    Bp0[i].u4[0] = BLo[r0];       Bp0[i].u4[1] = BHi[r0];
    Bp1[i].u4[0] = BLo[r0 + 256]; Bp1[i].u4[1] = BHi[r0 + 256];
  }

  // ---- A staging, coalesced (R9-verified): wave w owns rows [w*8,+8) ----
  {
    const int c4 = lane & 3;
    const int m  = lane >> 2;           // 0..15
    const float* zb = z + (rowbase + w * 8) * 512 + lane * 4;
    float p0 = 0.f, p1 = 0.f, p2 = 0.f, p3 = 0.f,
          p4 = 0.f, p5 = 0.f, p6 = 0.f, p7 = 0.f;
#pragma unroll
    for (int ss = 0; ss < 4; ++ss) {
      float4 f0 = *(const float4*)(zb + (2 * ss + 0) * 512);
      float4 f1 = *(const float4*)(zb + (2 * ss + 0) * 512 + 256);
      float4 f2 = *(const float4*)(zb + (2 * ss + 1) * 512);
      float4 f3 = *(const float4*)(zb + (2 * ss + 1) * 512 + 256);
      float sa = f0.x*f0.x + f0.y*f0.y + f0.z*f0.z + f0.w*f0.w
               + f1.x*f1.x + f1.y*f1.y + f1.z*f1.z + f1.w*f1.w;
      float sb = f2.x*f2.x + f2.y*f2.y + f2.z*f2.z + f2.w*f2.w
               + f3.x*f3.x + f3.y*f3.y + f3.z*f3.z + f3.w*f3.w;
      if (ss == 0) { p0 += sa; p1 += sb; }
      if (ss == 1) { p2 += sa; p3 += sb; }
      if (ss == 2) { p4 += sa; p5 += sb; }
      if (ss == 3) { p6 += sa; p7 += sb; }
      unsigned v0 = cvt4(f0.x, f0.y, f0.z, f0.w);
      unsigned v1 = cvt4(f1.x, f1.y, f1.z, f1.w);
      unsigned v2 = cvt4(f2.x, f2.y, f2.z, f2.w);
      unsigned v3 = cvt4(f3.x, f3.y, f3.z, f3.w);
      unsigned t;
      // stage A (xor 1): swap index-bit0 <-> lane-bit0
      t = (unsigned)__shfl_xor((int)((c4 & 1) ? v0 : v1), 1, 64);
      if (c4 & 1) v0 = t; else v1 = t;
      t = (unsigned)__shfl_xor((int)((c4 & 1) ? v2 : v3), 1, 64);
      if (c4 & 1) v2 = t; else v3 = t;
      // stage B (xor 2): swap index-bit1 <-> lane-bit1
      t = (unsigned)__shfl_xor((int)((c4 & 2) ? v0 : v2), 2, 64);
      if (c4 & 2) v0 = t; else v2 = t;
      t = (unsigned)__shfl_xor((int)((c4 & 2) ? v1 : v3), 2, 64);
      if (c4 & 2) v1 = t; else v3 = t;
      // lane holds granule: row 2ss+(c4>>1), K = 256*(c4&1) + 16*m
      int K   = ((c4 & 1) << 8) + (m << 4);
      int kb  = K >> 7;
      int kg  = (K >> 5) & 3;
      int pl  = (K >> 4) & 1;
      int r15 = ((w & 1) << 3) + 2 * ss + (c4 >> 1);
      int rf  = w >> 1;
      int ri  = pl * 1024 + (kb * 4 + rf) * 64 + kg * 16 + r15;
      As2[ri] = make_uint4(v0, v1, v2, v3);
    }
    // exact fp32 row sums: one wave-reduction per row
    float pr[8] = {p0, p1, p2, p3, p4, p5, p6, p7};
#pragma unroll
    for (int i = 0; i < 8; ++i) {
      float v = pr[i];
#pragma unroll
      for (int off = 32; off > 0; off >>= 1) v += __shfl_xor(v, off, 64);
      if (lane == 0) { x2s[w * 8 + i] = v; rxs[w * 8 + i] = 1.f / (1.f - v); }
    }
  }
  __syncthreads();  // the ONLY barrier before the final reduction

  // x2 resident per lane: rows rf*16 + q*4 + r
  float x2r[4][4];
#pragma unroll
  for (int rf = 0; rf < 4; ++rf) {
    float4 x4 = *(const float4*)&x2s[rf * 16 + q * 4];
    x2r[rf][0] = x4.x; x2r[rf][1] = x4.y; x2r[rf][2] = x4.z; x2r[rf][3] = x4.w;
  }

  float tmin[4][4];
#pragma unroll
  for (int rf = 0; rf < 4; ++rf)
#pragma unroll
    for (int r = 0; r < 4; ++r) tmin[rf][r] = 3.4e38f;

  const float* y2p = y2a + w * 256 + l15;
  const float* ryp = rya + w * 256 + l15;

#pragma clang loop unroll(disable)
  for (int t = 0; t < 8; ++t) {
    const int s = (t + w) & 7;      // rotated phase: wave w leads by w steps
    f32x4 acc[4][2];
#pragma unroll
    for (int rf = 0; rf < 4; ++rf) {
      f32x4 z4 = {0.f, 0.f, 0.f, 0.f};
      acc[rf][0] = z4; acc[rf][1] = z4;
    }
    float y2v0 = y2p[s * 32],      ryv0 = ryp[s * 32];
    float y2v1 = y2p[s * 32 + 16], ryv1 = ryp[s * 32 + 16];

#pragma unroll
    for (int kb = 0; kb < 4; ++kb) {
      // consume slot kb&1 (loaded 2 steps ago)
      __builtin_amdgcn_s_setprio(1);
#pragma unroll
      for (int rf = 0; rf < 4; ++rf) {
        A32 a;
        int ri = (kb * 4 + rf) * 64 + lane;
        a.u4[0] = As2[ri];
        a.u4[1] = As2[1024 + ri];
        acc[rf][0] = MFMA128(a.v, Bp0[kb & 1].v, acc[rf][0]);
        acc[rf][1] = MFMA128(a.v, Bp1[kb & 1].v, acc[rf][1]);
      }
      __builtin_amdgcn_s_setprio(0);
      {  // prefetch rotated step i+2 into the just-consumed slot
        int ip  = t * 4 + kb + 2;
        int sp  = ((ip >> 2) + w) & 7;       // wraps to s0 at the tail (safe)
        size_t r0 = (size_t)(w * 64 + sp * 8 + (ip & 3)) * 64 + lane;
        Bp0[kb & 1].u4[0] = BLo[r0];       Bp0[kb & 1].u4[1] = BHi[r0];
        Bp1[kb & 1].u4[0] = BLo[r0 + 256]; Bp1[kb & 1].u4[1] = BHi[r0 + 256];
      }
    }

    // epilogue: cols c0 = w*256 + s*32 + l15, c1 = c0 + 16
#pragma unroll
    for (int rf = 0; rf < 4; ++rf) {
#pragma unroll
      for (int r = 0; r < 4; ++r) {
        float xv = x2r[rf][r];
        float u0 = fmaxf(fmaf(-2.f, acc[rf][0][r], xv + y2v0), 0.f) * ryv0;
        float u1 = fmaxf(fmaf(-2.f, acc[rf][1][r], xv + y2v1), 0.f) * ryv1;
        tmin[rf][r] = fminf(tmin[rf][r], fminf(u0, u1));
      }
    }
  }

  // ---- min across the 16 lanes (l15) sharing each row ----
#pragma unroll
  for (int rf = 0; rf < 4; ++rf) {
#pragma unroll
    for (int r = 0; r < 4; ++r) {
      float v = tmin[rf][r];
      v = fminf(v, __shfl_xor(v, 1, 64));
      v = fminf(v, __shfl_xor(v, 2, 64));
      v = fminf(v, __shfl_xor(v, 4, 64));
      v = fminf(v, __shfl_xor(v, 8, 64));
      if (l15 == 0) minbuf[rf * 16 + q * 4 + r][w] = v;
    }
  }
  __syncthreads();

  if (w == 0) {  // lane = row 0..63
    float m = minbuf[lane][0];
#pragma unroll
    for (int i = 1; i < 8; ++i) m = fminf(m, minbuf[lane][i]);
    float t = m * rxs[lane];                 // fold 1/(1-x2) once per row
    float arg = fmaxf(fmaf(2.f, t, 1.f), 1.f + EPS_F);
    float contrib = fmaxf(marg[0] - acoshf(arg), 0.f);
#pragma unroll
    for (int off = 32; off > 0; off >>= 1) contrib += __shfl_xor(contrib, off, 64);
    if (lane == 0) atomicAdd(out, contrib * (1.0f / 32768.f));
  }
}

// ---------------------------------------------------------------------------
extern "C" void kernel_launch(void* const* d_in, const int* in_sizes, int n_in,
                              void* d_out, int out_size, void* d_ws, size_t ws_size,
                              hipStream_t stream) {
  const float* z      = (const float*)d_in[0];  // 32768 x 512 fp32
  const float* protos = (const float*)d_in[1];  // 2048 x 512 fp32
  const float* marg   = (const float*)d_in[2];  // scalar
  float* out = (float*)d_out;
  uint8_t* wsB = (uint8_t*)d_ws;                // 1 MB image (lo/hi 512 KB planes)
  // 192 KB pad retained (tail prefetch now wraps in-bounds, pad unused).
  float* y2a = (float*)((char*)d_ws + (1 << 20) + 192 * 1024);   // 8 KB
  float* rya = y2a + 2048;                                       // 8 KB

  prep_kernel<<<512, 256, 0, stream>>>(protos, wsB, y2a, rya, out);
  gemm_min_kernel<<<512, 512, 0, stream>>>(z, wsB, y2a, rya, marg, out);
}

// Round 13
// 126.706 us; speedup vs baseline: 1.1854x; 1.0189x over previous
//
#include <hip/hip_runtime.h>
#include <stdint.h>

#define EPS_F 1e-7f

typedef float f32x4 __attribute__((ext_vector_type(4)));
typedef int   v8i   __attribute__((ext_vector_type(8)));

// 8 consecutive VGPRs: two b128 loads land directly in the MFMA operand tuple.
union A32 { uint4 u4[2]; v8i v; };

__device__ __forceinline__ unsigned cvt4(float a, float b, float c, float d) {
  int v = __builtin_amdgcn_cvt_pk_fp8_f32(a, b, 0, false);   // bytes 0,1
  return (unsigned)__builtin_amdgcn_cvt_pk_fp8_f32(c, d, v, true);  // bytes 2,3
}

// MX-scaled fp8 MFMA, K=128, scales = 1.0 (e8m0 127 in every byte -> opsel-proof).
#define MFMA128(A, B, C) __builtin_amdgcn_mfma_scale_f32_16x16x128_f8f6f4( \
    (A), (B), (C), 0, 0, 0, 0x7F7F7F7F, 0, 0x7F7F7F7F)

// ---------------------------------------------------------------------------
// Shared software k-order for BOTH operand images (R5-R12 verified, absmax 0):
//   fragment lane = kg*16 + (row|col)&15,  kg = lane>>4
//   nominal k  = kb*128 + kg*32 + j,  j in [0,32)
//   j in [0,16)  -> LO plane,  j in [16,32) -> HI plane
// B image: run index ri = (g*4 + kb)*64 + lane, planes of 512 KB each.
// ---------------------------------------------------------------------------

// ---------------------------------------------------------------------------
// prep: protos fp32 (2048x512) -> fp8 e4m3 B image (layout unchanged).
// Per-column epilogue constants packed as float2 c2a[c] = {-2ry, y2*ry}
// (ry = 1/(1-y2); clamp never binds, points inside radius-0.8 ball).
// ---------------------------------------------------------------------------
__global__ __launch_bounds__(256) void prep_kernel(
    const float* __restrict__ protos, uint8_t* __restrict__ wsB,
    float2* __restrict__ c2a, float* __restrict__ out) {
  const int lane = threadIdx.x & 63;
  const int w    = threadIdx.x >> 6;
  const int c    = blockIdx.x * 4 + w;
  const int g    = c >> 4, cl = c & 15;
  const float4* p = (const float4*)(protos + (size_t)c * 512 + lane * 8);
  float4 f0 = p[0], f1 = p[1];
  float s = f0.x*f0.x + f0.y*f0.y + f0.z*f0.z + f0.w*f0.w
          + f1.x*f1.x + f1.y*f1.y + f1.z*f1.z + f1.w*f1.w;
#pragma unroll
  for (int off = 32; off > 0; off >>= 1) s += __shfl_xor(s, off, 64);
  if (lane == 0) {
    float ry = 1.f / (1.f - s);
    c2a[c] = make_float2(-2.f * ry, s * ry);
  }
  unsigned ux = cvt4(f0.x, f0.y, f0.z, f0.w);   // k [8l, 8l+4)
  unsigned uy = cvt4(f1.x, f1.y, f1.z, f1.w);   // k [8l+4, 8l+8)
  const int kb = lane >> 4, kg = (lane >> 2) & 3, bo = lane & 3;
  size_t ri  = (size_t)(g * 4 + kb) * 64 + kg * 16 + cl;
  size_t off = ri * 16 + (size_t)(bo & 1) * 8 + (size_t)(bo >> 1) * (512u * 1024u);
  *(uint2*)(wsB + off) = make_uint2(ux, uy);
  if (blockIdx.x == 0 && threadIdx.x == 0) out[0] = 0.f;
}

// ---------------------------------------------------------------------------
// gemm_min v13: VALU DIET on the R12 winner (phase-rotated waves + setprio,
// 55 us steady, first confirmed scheduling win).  512 blocks x 512 thr
// (8 waves), launch_bounds(512,1) -> VGPR cap 128 (R6/R7/R9/R12: no spill).
// ROUND-12 POST-MORTEM: rotation+setprio -8% confirmed the phase-stall
// mechanism; counters now show VALUBusy (31%) > MfmaUtil (24.6%) -> VALU is
// the largest issue-cycle consumer and sits between MFMA clusters at 2
// waves/SIMD.  Cuts (algebraically exact):
//   1. fmax(u,0) DROPPED: any negative u (only when true sqdist < fp8 err)
//      maps through arg = max(1+2t, 1+EPS) to the same d~0 as the clamped
//      path -> bitwise-equivalent loss contribution.
//   2. u = fma(m2ry, acc, fma(m2ry, hx, y2ry)) with per-col {m2ry, y2ry}
//      precomputed in prep and per-row hx = -x2/2: 2 fma + 1 min per
//      element (was add+fma+max+mul+min).  Identity: (-2ry)(-x2/2) + y2*ry
//      + (-2ry)d = ry*(x2+y2-2d).
//   3. acc zero-init through the MFMA C operand (kb==0 reads shared zero4):
//      kills 32 accvgpr writes per s-iter.
// Everything else byte-identical to R12 (coalesced transpose staging,
// depth-2 B pipeline, rotated s = (t+w)&7, setprio around MFMA clusters,
// one barrier).
// ---------------------------------------------------------------------------
__global__ __launch_bounds__(512, 1) void gemm_min_kernel(
    const float* __restrict__ z, const uint8_t* __restrict__ wsB,
    const float2* __restrict__ c2a,
    const float* __restrict__ marg, float* __restrict__ out) {
  __shared__ uint4 As2[2048];    // [pl*1024 + (kb*4+rf)*64 + kg*16 + r15]  32 KB
  __shared__ float x2s[64];
  __shared__ float rxs[64];
  __shared__ float minbuf[64][8];

  const int tid  = threadIdx.x;
  const int lane = tid & 63;
  const int w    = tid >> 6;          // wave 0..7
  const int q    = lane >> 4;         // kg / acc row-group
  const int l15  = lane & 15;
  const size_t rowbase = (size_t)blockIdx.x * 64;

  const uint4* BLo = (const uint4*)wsB;
  const uint4* BHi = BLo + 32768;     // +512 KB

  // ---- B warm-up (rotated steps t=0, kb=0,1): s0 = w ----
  A32 Bp0[2], Bp1[2];
#pragma unroll
  for (int i = 0; i < 2; ++i) {
    size_t r0 = (size_t)(w * 64 + (w & 7) * 8 + i) * 64 + lane;
    Bp0[i].u4[0] = BLo[r0];       Bp0[i].u4[1] = BHi[r0];
    Bp1[i].u4[0] = BLo[r0 + 256]; Bp1[i].u4[1] = BHi[r0 + 256];
  }

  // ---- A staging, coalesced (R9-verified): wave w owns rows [w*8,+8) ----
  {
    const int c4 = lane & 3;
    const int m  = lane >> 2;           // 0..15
    const float* zb = z + (rowbase + w * 8) * 512 + lane * 4;
    float p0 = 0.f, p1 = 0.f, p2 = 0.f, p3 = 0.f,
          p4 = 0.f, p5 = 0.f, p6 = 0.f, p7 = 0.f;
#pragma unroll
    for (int ss = 0; ss < 4; ++ss) {
      float4 f0 = *(const float4*)(zb + (2 * ss + 0) * 512);
      float4 f1 = *(const float4*)(zb + (2 * ss + 0) * 512 + 256);
      float4 f2 = *(const float4*)(zb + (2 * ss + 1) * 512);
      float4 f3 = *(const float4*)(zb + (2 * ss + 1) * 512 + 256);
      float sa = f0.x*f0.x + f0.y*f0.y + f0.z*f0.z + f0.w*f0.w
               + f1.x*f1.x + f1.y*f1.y + f1.z*f1.z + f1.w*f1.w;
      float sb = f2.x*f2.x + f2.y*f2.y + f2.z*f2.z + f2.w*f2.w
               + f3.x*f3.x + f3.y*f3.y + f3.z*f3.z + f3.w*f3.w;
      if (ss == 0) { p0 += sa; p1 += sb; }
      if (ss == 1) { p2 += sa; p3 += sb; }
      if (ss == 2) { p4 += sa; p5 += sb; }
      if (ss == 3) { p6 += sa; p7 += sb; }
      unsigned v0 = cvt4(f0.x, f0.y, f0.z, f0.w);
      unsigned v1 = cvt4(f1.x, f1.y, f1.z, f1.w);
      unsigned v2 = cvt4(f2.x, f2.y, f2.z, f2.w);
      unsigned v3 = cvt4(f3.x, f3.y, f3.z, f3.w);
      unsigned t;
      // stage A (xor 1): swap index-bit0 <-> lane-bit0
      t = (unsigned)__shfl_xor((int)((c4 & 1) ? v0 : v1), 1, 64);
      if (c4 & 1) v0 = t; else v1 = t;
      t = (unsigned)__shfl_xor((int)((c4 & 1) ? v2 : v3), 1, 64);
      if (c4 & 1) v2 = t; else v3 = t;
      // stage B (xor 2): swap index-bit1 <-> lane-bit1
      t = (unsigned)__shfl_xor((int)((c4 & 2) ? v0 : v2), 2, 64);
      if (c4 & 2) v0 = t; else v2 = t;
      t = (unsigned)__shfl_xor((int)((c4 & 2) ? v1 : v3), 2, 64);
      if (c4 & 2) v1 = t; else v3 = t;
      // lane holds granule: row 2ss+(c4>>1), K = 256*(c4&1) + 16*m
      int K   = ((c4 & 1) << 8) + (m << 4);
      int kb  = K >> 7;
      int kg  = (K >> 5) & 3;
      int pl  = (K >> 4) & 1;
      int r15 = ((w & 1) << 3) + 2 * ss + (c4 >> 1);
      int rf  = w >> 1;
      int ri  = pl * 1024 + (kb * 4 + rf) * 64 + kg * 16 + r15;
      As2[ri] = make_uint4(v0, v1, v2, v3);
    }
    // exact fp32 row sums: one wave-reduction per row
    float pr[8] = {p0, p1, p2, p3, p4, p5, p6, p7};
#pragma unroll
    for (int i = 0; i < 8; ++i) {
      float v = pr[i];
#pragma unroll
      for (int off = 32; off > 0; off >>= 1) v += __shfl_xor(v, off, 64);
      if (lane == 0) { x2s[w * 8 + i] = v; rxs[w * 8 + i] = 1.f / (1.f - v); }
    }
  }
  __syncthreads();  // the ONLY barrier before the final reduction

  // per-lane row constants hx = -x2/2: rows rf*16 + q*4 + r
  float x2r[4][4];
#pragma unroll
  for (int rf = 0; rf < 4; ++rf) {
    float4 x4 = *(const float4*)&x2s[rf * 16 + q * 4];
    x2r[rf][0] = -0.5f * x4.x; x2r[rf][1] = -0.5f * x4.y;
    x2r[rf][2] = -0.5f * x4.z; x2r[rf][3] = -0.5f * x4.w;
  }

  float tmin[4][4];
#pragma unroll
  for (int rf = 0; rf < 4; ++rf)
#pragma unroll
    for (int r = 0; r < 4; ++r) tmin[rf][r] = 3.4e38f;

  const float2* cp = c2a + w * 256 + l15;
  const f32x4 zero4 = {0.f, 0.f, 0.f, 0.f};

#pragma clang loop unroll(disable)
  for (int t = 0; t < 8; ++t) {
    const int s = (t + w) & 7;      // rotated phase: wave w leads by w steps
    f32x4 acc[4][2];
    float2 q0 = cp[s * 32], q1 = cp[s * 32 + 16];   // {m2ry, y2ry}

#pragma unroll
    for (int kb = 0; kb < 4; ++kb) {
      // consume slot kb&1 (loaded 2 steps ago)
      __builtin_amdgcn_s_setprio(1);
#pragma unroll
      for (int rf = 0; rf < 4; ++rf) {
        A32 a;
        int ri = (kb * 4 + rf) * 64 + lane;
        a.u4[0] = As2[ri];
        a.u4[1] = As2[1024 + ri];
        if (kb == 0) {  // zero-init through the C operand (no accvgpr movs)
          acc[rf][0] = MFMA128(a.v, Bp0[0].v, zero4);
          acc[rf][1] = MFMA128(a.v, Bp1[0].v, zero4);
        } else {
          acc[rf][0] = MFMA128(a.v, Bp0[kb & 1].v, acc[rf][0]);
          acc[rf][1] = MFMA128(a.v, Bp1[kb & 1].v, acc[rf][1]);
        }
      }
      __builtin_amdgcn_s_setprio(0);
      {  // prefetch rotated step i+2 into the just-consumed slot
        int ip  = t * 4 + kb + 2;
        int sp  = ((ip >> 2) + w) & 7;       // wraps to s0 at the tail (safe)
        size_t r0 = (size_t)(w * 64 + sp * 8 + (ip & 3)) * 64 + lane;
        Bp0[kb & 1].u4[0] = BLo[r0];       Bp0[kb & 1].u4[1] = BHi[r0];
        Bp1[kb & 1].u4[0] = BLo[r0 + 256]; Bp1[kb & 1].u4[1] = BHi[r0 + 256];
      }
    }

    // epilogue: cols c0 = w*256 + s*32 + l15, c1 = c0 + 16
    // u = m2ry*hx + y2ry + m2ry*d  =  ry*(x2 + y2 - 2d)   (2 fma + min)
#pragma unroll
    for (int rf = 0; rf < 4; ++rf) {
#pragma unroll
      for (int r = 0; r < 4; ++r) {
        float hx = x2r[rf][r];
        float u0 = fmaf(q0.x, acc[rf][0][r], fmaf(q0.x, hx, q0.y));
        float u1 = fmaf(q1.x, acc[rf][1][r], fmaf(q1.x, hx, q1.y));
        tmin[rf][r] = fminf(tmin[rf][r], fminf(u0, u1));
      }
    }
  }

  // ---- min across the 16 lanes (l15) sharing each row ----
#pragma unroll
  for (int rf = 0; rf < 4; ++rf) {
#pragma unroll
    for (int r = 0; r < 4; ++r) {
      float v = tmin[rf][r];
      v = fminf(v, __shfl_xor(v, 1, 64));
      v = fminf(v, __shfl_xor(v, 2, 64));
      v = fminf(v, __shfl_xor(v, 4, 64));
      v = fminf(v, __shfl_xor(v, 8, 64));
      if (l15 == 0) minbuf[rf * 16 + q * 4 + r][w] = v;
    }
  }
  __syncthreads();

  if (w == 0) {  // lane = row 0..63
    float m = minbuf[lane][0];
#pragma unroll
    for (int i = 1; i < 8; ++i) m = fminf(m, minbuf[lane][i]);
    float t = m * rxs[lane];                 // fold 1/(1-x2) once per row
    float arg = fmaxf(fmaf(2.f, t, 1.f), 1.f + EPS_F);  // clamps u<0 too
    float contrib = fmaxf(marg[0] - acoshf(arg), 0.f);
#pragma unroll
    for (int off = 32; off > 0; off >>= 1) contrib += __shfl_xor(contrib, off, 64);
    if (lane == 0) atomicAdd(out, contrib * (1.0f / 32768.f));
  }
}

// ---------------------------------------------------------------------------
extern "C" void kernel_launch(void* const* d_in, const int* in_sizes, int n_in,
                              void* d_out, int out_size, void* d_ws, size_t ws_size,
                              hipStream_t stream) {
  const float* z      = (const float*)d_in[0];  // 32768 x 512 fp32
  const float* protos = (const float*)d_in[1];  // 2048 x 512 fp32
  const float* marg   = (const float*)d_in[2];  // scalar
  float* out = (float*)d_out;
  uint8_t* wsB = (uint8_t*)d_ws;                // 1 MB image (lo/hi 512 KB planes)
  // 192 KB pad retained (rotated prefetch wraps in-bounds, pad unused).
  float2* c2a = (float2*)((char*)d_ws + (1 << 20) + 192 * 1024);  // 16 KB

  prep_kernel<<<512, 256, 0, stream>>>(protos, wsB, c2a, out);
  gemm_min_kernel<<<512, 512, 0, stream>>>(z, wsB, c2a, marg, out);
}